// Round 1
// 2323.290 us; speedup vs baseline: 1.6520x; 1.6520x over previous
//
#include <hip/hip_runtime.h>
#include <math.h>

#define NB 65536
#define ND 512
#define NK 1024
#define NL 4
#define THR 1e-3f

typedef __attribute__((ext_vector_type(8))) short short8;
typedef __attribute__((ext_vector_type(4))) float floatx4;

__device__ inline unsigned short bf16_rne(float x) {
  unsigned int u = __float_as_uint(x);
  unsigned int r = u + 0x7FFFu + ((u >> 16) & 1u);
  return (unsigned short)(r >> 16);
}

// ---------------- cn: per-code squared norms (fp64 accumulate, round to f32) ----------------
__global__ void cn_kernel(const float* __restrict__ cb, float* __restrict__ cn) {
  const int code = blockIdx.x;
  const float* row = cb + (size_t)code * ND;
  const int t = threadIdx.x;
  const float x = row[t];
  const float y = row[t + 256];
  double s = (double)x * x + (double)y * y;
  for (int off = 32; off > 0; off >>= 1) s += __shfl_down(s, off);
  __shared__ double part[4];
  if ((t & 63) == 0) part[t >> 6] = s;
  __syncthreads();
  if (t == 0) cn[code] = (float)(part[0] + part[1] + part[2] + part[3]);
}

// ---------------- rn: per-row squared norms (level 0; levels 1-3 fused into update) ----
__global__ void rn_kernel(const float* __restrict__ x, float* __restrict__ rn) {
  const int t = threadIdx.x;
  const int row = blockIdx.x * 2 + (t >> 7);
  const int c = (t & 127) << 2;
  const float4 v = *(const float4*)(x + (size_t)row * ND + c);
  double s = (double)v.x * v.x + (double)v.y * v.y + (double)v.z * v.z + (double)v.w * v.w;
  for (int off = 32; off > 0; off >>= 1) s += __shfl_down(s, off);
  __shared__ double part[4];
  if ((t & 63) == 0) part[t >> 6] = s;
  __syncthreads();
  if ((t & 127) == 0) rn[row] = (float)(part[t >> 6] + part[(t >> 6) + 1]);
}

// ---------------- bf16 3-term split MFMA distance + candidate collection ----------------
// dot_approx = hi_a*hi_b + lo_a*hi_b + hi_a*lo_b (fp32 MFMA acc). |d2a - d2_exact| <= ~1.4e-4.
// Collect k with d2a <= blockchunk_rowmin + THR into per-row candidate list; exact argmin is
// provably in the list (see analysis). Recheck kernel resolves with bit-exact fp32 chain.
__global__ __launch_bounds__(512, 2)
void argmin_mfma(const float* __restrict__ res,   // [NB, ND]
                 const float* __restrict__ cb,    // [NK, ND] (this level)
                 const float* __restrict__ rn,    // [NB]
                 const float* __restrict__ cn,    // [NK] (this level)
                 unsigned int* __restrict__ cnt,  // [NB]
                 unsigned int* __restrict__ cand) { // [NB*16]
  __shared__ short A_hi[128][40];   // [m][k] bf16, pad 40 (80B rows -> 20-bank rotation)
  __shared__ short A_lo[128][40];
  __shared__ short B_hi[256][40];   // [n][k] bf16
  __shared__ short B_lo[256][40];
  __shared__ float minbuf[128][4];

  const int t = threadIdx.x;
  const int lane = t & 63;
  const int w = t >> 6;             // wave 0..7
  const int wr = w >> 2;            // 0..1  (row group of 64)
  const int wc = w & 3;             // 0..3  (col group of 64)
  const int q = lane >> 4;          // quad 0..3
  const int col16 = lane & 15;
  const int rowbase = (blockIdx.x >> 1) * 128;
  const int cbase = (blockIdx.x & 1) * 512;

  // staging maps
  const int sa_row = t >> 2, sa_k = (t & 3) * 8;    // A: 8 f32/thread
  const int sb_row = t >> 1, sb_k = (t & 1) * 16;   // B: 16 f32/thread

  for (int nc = 0; nc < 2; ++nc) {
    floatx4 acc[4][4];
#pragma unroll
    for (int i = 0; i < 4; ++i)
#pragma unroll
      for (int j = 0; j < 4; ++j) acc[i][j] = (floatx4){0.f, 0.f, 0.f, 0.f};

    // prefetch kc=0
    float4 fa0, fa1, fb[4];
    {
      const float* ap = res + (size_t)(rowbase + sa_row) * ND + sa_k;
      fa0 = *(const float4*)(ap);
      fa1 = *(const float4*)(ap + 4);
      const float* bp = cb + (size_t)(cbase + nc * 256 + sb_row) * ND + sb_k;
#pragma unroll
      for (int j = 0; j < 4; ++j) fb[j] = *(const float4*)(bp + 4 * j);
    }

    for (int kc = 0; kc < 16; ++kc) {
      __syncthreads();
      // convert + write LDS
      {
        float av[8] = {fa0.x, fa0.y, fa0.z, fa0.w, fa1.x, fa1.y, fa1.z, fa1.w};
        short8 h, l;
#pragma unroll
        for (int j = 0; j < 8; ++j) {
          unsigned short hb = bf16_rne(av[j]);
          float hf = __uint_as_float((unsigned int)hb << 16);
          h[j] = (short)hb;
          l[j] = (short)bf16_rne(av[j] - hf);
        }
        *(short8*)&A_hi[sa_row][sa_k] = h;
        *(short8*)&A_lo[sa_row][sa_k] = l;
        float bv[16];
#pragma unroll
        for (int j = 0; j < 4; ++j) {
          bv[4 * j + 0] = fb[j].x; bv[4 * j + 1] = fb[j].y;
          bv[4 * j + 2] = fb[j].z; bv[4 * j + 3] = fb[j].w;
        }
        short8 h0, l0, h1, l1;
#pragma unroll
        for (int j = 0; j < 8; ++j) {
          unsigned short hb = bf16_rne(bv[j]);
          float hf = __uint_as_float((unsigned int)hb << 16);
          h0[j] = (short)hb;
          l0[j] = (short)bf16_rne(bv[j] - hf);
          unsigned short hb1 = bf16_rne(bv[j + 8]);
          float hf1 = __uint_as_float((unsigned int)hb1 << 16);
          h1[j] = (short)hb1;
          l1[j] = (short)bf16_rne(bv[j + 8] - hf1);
        }
        *(short8*)&B_hi[sb_row][sb_k] = h0;
        *(short8*)&B_lo[sb_row][sb_k] = l0;
        *(short8*)&B_hi[sb_row][sb_k + 8] = h1;
        *(short8*)&B_lo[sb_row][sb_k + 8] = l1;
      }
      __syncthreads();
      if (kc + 1 < 16) {  // prefetch next chunk
        const float* ap = res + (size_t)(rowbase + sa_row) * ND + (kc + 1) * 32 + sa_k;
        fa0 = *(const float4*)(ap);
        fa1 = *(const float4*)(ap + 4);
        const float* bp = cb + (size_t)(cbase + nc * 256 + sb_row) * ND + (kc + 1) * 32 + sb_k;
#pragma unroll
        for (int j = 0; j < 4; ++j) fb[j] = *(const float4*)(bp + 4 * j);
      }
      // fragment loads + MFMA
      short8 ahi[4], alo[4], bhi[4], blo[4];
#pragma unroll
      for (int ti = 0; ti < 4; ++ti) {
        const int m = wr * 64 + ti * 16 + col16;
        ahi[ti] = *(short8*)&A_hi[m][q * 8];
        alo[ti] = *(short8*)&A_lo[m][q * 8];
      }
#pragma unroll
      for (int tj = 0; tj < 4; ++tj) {
        const int n = wc * 64 + tj * 16 + col16;
        bhi[tj] = *(short8*)&B_hi[n][q * 8];
        blo[tj] = *(short8*)&B_lo[n][q * 8];
      }
#pragma unroll
      for (int ti = 0; ti < 4; ++ti)
#pragma unroll
        for (int tj = 0; tj < 4; ++tj) {
          acc[ti][tj] = __builtin_amdgcn_mfma_f32_16x16x32_bf16(ahi[ti], bhi[tj], acc[ti][tj], 0, 0, 0);
          acc[ti][tj] = __builtin_amdgcn_mfma_f32_16x16x32_bf16(alo[ti], bhi[tj], acc[ti][tj], 0, 0, 0);
          acc[ti][tj] = __builtin_amdgcn_mfma_f32_16x16x32_bf16(ahi[ti], blo[tj], acc[ti][tj], 0, 0, 0);
        }
    }

    // ---- epilogue for this nc: d2a, per-row chunk min, collect candidates ----
    float rnv[16], cnv[4];
#pragma unroll
    for (int ti = 0; ti < 4; ++ti)
#pragma unroll
      for (int v = 0; v < 4; ++v)
        rnv[ti * 4 + v] = rn[rowbase + wr * 64 + ti * 16 + q * 4 + v];
#pragma unroll
    for (int tj = 0; tj < 4; ++tj)
      cnv[tj] = cn[cbase + nc * 256 + wc * 64 + tj * 16 + col16];

    float rm[16];
#pragma unroll
    for (int ti = 0; ti < 4; ++ti)
#pragma unroll
      for (int v = 0; v < 4; ++v) {
        float m0 = INFINITY;
#pragma unroll
        for (int tj = 0; tj < 4; ++tj) {
          const float d2 = (rnv[ti * 4 + v] + cnv[tj]) - 2.0f * acc[ti][tj][v];
          m0 = fminf(m0, d2);
        }
        rm[ti * 4 + v] = m0;
      }
#pragma unroll
    for (int mask = 1; mask < 16; mask <<= 1)
#pragma unroll
      for (int i = 0; i < 16; ++i) rm[i] = fminf(rm[i], __shfl_xor(rm[i], mask));
    if (col16 == 0) {
#pragma unroll
      for (int ti = 0; ti < 4; ++ti)
#pragma unroll
        for (int v = 0; v < 4; ++v)
          minbuf[wr * 64 + ti * 16 + q * 4 + v][wc] = rm[ti * 4 + v];
    }
    __syncthreads();
    if (t < 128)
      minbuf[t][0] = fminf(fminf(minbuf[t][0], minbuf[t][1]), fminf(minbuf[t][2], minbuf[t][3]));
    __syncthreads();
#pragma unroll
    for (int ti = 0; ti < 4; ++ti)
#pragma unroll
      for (int v = 0; v < 4; ++v) {
        const int grow = rowbase + wr * 64 + ti * 16 + q * 4 + v;
        const float thrv = minbuf[wr * 64 + ti * 16 + q * 4 + v][0] + THR;
#pragma unroll
        for (int tj = 0; tj < 4; ++tj) {
          const float d2 = (rnv[ti * 4 + v] + cnv[tj]) - 2.0f * acc[ti][tj][v];
          if (d2 <= thrv) {
            const unsigned int gcol = cbase + nc * 256 + wc * 64 + tj * 16 + col16;
            const unsigned int slot = atomicAdd(&cnt[grow], 1u);
            if (slot < 16) cand[(size_t)grow * 16 + slot] = gcol;
          }
        }
      }
    __syncthreads();
  }
}

// ---------------- exact recheck: bit-identical fp32 chain over candidates ----------------
// New layout: 16 rows x 4 candidate slots per wave (lane = 4*r_local + slot).
// Each (row, cand) d2 is computed on ONE lane with the same sequential fmaf chain as
// before -> identical d2 bits, identical (d2, k) lexicographic-min result. Rows with
// cnt > 16 fall back to the identical whole-wave full scan (rare).
__global__ __launch_bounds__(256)
void recheck_kernel(const float* __restrict__ res, const float* __restrict__ cb,
                    const float* __restrict__ rn, const float* __restrict__ cn,
                    const unsigned int* __restrict__ cnt,
                    const unsigned int* __restrict__ cand,
                    int* __restrict__ idx) {
  const int t = threadIdx.x;
  const int lane = t & 63;
  const int slot = lane & 3;
  const int row = blockIdx.x * 64 + (t >> 2);          // 16 rows per wave
  const int wavebase = blockIdx.x * 64 + (t >> 6) * 16;
  const unsigned int c = cnt[row];
  const float* rp = res + (size_t)row * ND;
  const float rnr = rn[row];

  if (c <= 16) {
    float bestv = INFINITY;
    int bestk = 0x7fffffff;
    for (unsigned int s = slot; s < c; s += 4) {
      const int k = (int)cand[(size_t)row * 16 + s];
      const float* cp = cb + (size_t)k * ND;
      float acc = 0.f;
#pragma unroll 8
      for (int d = 0; d < ND; d += 4) {
        const float4 rv = *(const float4*)(rp + d);
        const float4 cv = *(const float4*)(cp + d);
        acc = fmaf(rv.x, cv.x, acc);
        acc = fmaf(rv.y, cv.y, acc);
        acc = fmaf(rv.z, cv.z, acc);
        acc = fmaf(rv.w, cv.w, acc);
      }
      const float d2 = (rnr + cn[k]) - 2.0f * acc;
      if (d2 < bestv || (d2 == bestv && k < bestk)) { bestv = d2; bestk = k; }
    }
    // reduce across the 4 slot-lanes of this row (all 4 share the same c, so no
    // divergence inside the shuffle group)
#pragma unroll
    for (int off = 1; off < 4; off <<= 1) {
      const float ov = __shfl_xor(bestv, off);
      const int ok = __shfl_xor(bestk, off);
      if (ov < bestv || (ov == bestv && ok < bestk)) { bestv = ov; bestk = ok; }
    }
    if (slot == 0) idx[row] = bestk;
  }

  // overflow rows (c > 16): whole-wave exact scan of all NK codes, identical to the
  // previous fallback path (same per-lane chain, same tie-break, same reduction).
  unsigned long long ovf = __ballot(slot == 0 && c > 16);
  while (ovf) {
    const int src = (int)__ffsll(ovf) - 1;   // lane index (slot0) of an overflow row
    ovf &= ovf - 1;
    const int orow = wavebase + (src >> 2);
    const float* orp = res + (size_t)orow * ND;
    const float ornr = rn[orow];
    float bv = INFINITY;
    int bk = 0x7fffffff;
    for (int kk = 0; kk < NK; kk += 64) {
      const int k = kk + lane;
      const float* cp = cb + (size_t)k * ND;
      float acc = 0.f;
      for (int d = 0; d < ND; d += 4) {
        const float4 rv = *(const float4*)(orp + d);
        const float4 cv = *(const float4*)(cp + d);
        acc = fmaf(rv.x, cv.x, acc);
        acc = fmaf(rv.y, cv.y, acc);
        acc = fmaf(rv.z, cv.z, acc);
        acc = fmaf(rv.w, cv.w, acc);
      }
      const float d2 = (ornr + cn[k]) - 2.0f * acc;
      if (d2 < bv || (d2 == bv && k < bk)) { bv = d2; bk = k; }
    }
    for (int off = 32; off > 0; off >>= 1) {
      const float ov = __shfl_down(bv, off);
      const int ok = __shfl_down(bk, off);
      if (ov < bv || (ov == bv && ok < bk)) { bv = ov; bk = ok; }
    }
    if (lane == 0) idx[orow] = bk;
  }
}

// ---------------- residual update + next-level rn + loss partial + codes ----------------
__global__ void update_kernel(const float* __restrict__ res_in,
                              const float* __restrict__ cb,
                              const int* __restrict__ idx,
                              float* __restrict__ res_out,
                              float* __restrict__ codes_out,
                              float* __restrict__ rn_out,
                              double* __restrict__ lacc) {
  const int t = threadIdx.x;
  const int row = blockIdx.x * 2 + (t >> 7);
  const int c = (t & 127) << 2;
  const int k = idx[row];
  const float4 r = *(const float4*)(res_in + (size_t)row * ND + c);
  const float4 q = *(const float4*)(cb + (size_t)k * ND + c);
  float4 nr;
  nr.x = r.x - q.x; nr.y = r.y - q.y; nr.z = r.z - q.z; nr.w = r.w - q.w;
  *(float4*)(res_out + (size_t)row * ND + c) = nr;
  if (c == 0) codes_out[row] = (float)k;
  double s = (double)nr.x * nr.x + (double)nr.y * nr.y +
             (double)nr.z * nr.z + (double)nr.w * nr.w;
  for (int off = 32; off > 0; off >>= 1) s += __shfl_down(s, off);
  __shared__ double part[4];
  if ((t & 63) == 0) part[t >> 6] = s;
  __syncthreads();
  if ((t & 127) == 0) rn_out[row] = (float)(part[t >> 6] + part[(t >> 6) + 1]);
  if (t == 0) atomicAdd(&lacc[blockIdx.x & 511], part[0] + part[1] + part[2] + part[3]);
}

// ---------------- loss: reduce 4*512 slots -> scalar ----------------
__global__ void loss_reduce(const double* __restrict__ lacc, float* __restrict__ out) {
  const int t = threadIdx.x;
  double s = 0.0;
  for (int i = t; i < NL * 512; i += 256) s += lacc[i];
  for (int off = 32; off > 0; off >>= 1) s += __shfl_down(s, off);
  __shared__ double part[4];
  if ((t & 63) == 0) part[t >> 6] = s;
  __syncthreads();
  if (t == 0)
    out[(size_t)NB * ND + (size_t)NL * NB] =
        (float)(2.0 * (part[0] + part[1] + part[2] + part[3]) / ((double)NB * (double)ND));
}

// ---------------- finalize: z_q_st (codes already in out) ----------------
__global__ void final_kernel(const float* __restrict__ z_e,
                             const float* __restrict__ cbs,
                             float* __restrict__ out) {
  const size_t gid = (size_t)blockIdx.x * 256 + threadIdx.x;
  const int row = (int)(gid >> 7);
  const int c = ((int)gid & 127) << 2;
  const float* codes = out + (size_t)NB * ND;
  const int k0 = (int)codes[0 * NB + row];
  const int k1 = (int)codes[1 * NB + row];
  const int k2 = (int)codes[2 * NB + row];
  const int k3 = (int)codes[3 * NB + row];
  const float4 q0 = *(const float4*)(cbs + ((size_t)0 * NK + k0) * ND + c);
  const float4 q1 = *(const float4*)(cbs + ((size_t)1 * NK + k1) * ND + c);
  const float4 q2 = *(const float4*)(cbs + ((size_t)2 * NK + k2) * ND + c);
  const float4 q3 = *(const float4*)(cbs + ((size_t)3 * NK + k3) * ND + c);
  const float4 z = *(const float4*)(z_e + (size_t)row * ND + c);
  float4 qs, o;
  qs.x = ((q0.x + q1.x) + q2.x) + q3.x;
  qs.y = ((q0.y + q1.y) + q2.y) + q3.y;
  qs.z = ((q0.z + q1.z) + q2.z) + q3.z;
  qs.w = ((q0.w + q1.w) + q2.w) + q3.w;
  o.x = z.x + (qs.x - z.x);
  o.y = z.y + (qs.y - z.y);
  o.z = z.z + (qs.z - z.z);
  o.w = z.w + (qs.w - z.w);
  *(float4*)(out + (size_t)row * ND + c) = o;
}

extern "C" void kernel_launch(void* const* d_in, const int* in_sizes, int n_in,
                              void* d_out, int out_size, void* d_ws, size_t ws_size,
                              hipStream_t stream) {
  const float* z_e = (const float*)d_in[0];
  const float* cbs = (const float*)d_in[1];
  float* out = (float*)d_out;
  char* ws = (char*)d_ws;

  // ws layout (~5 MB): lacc d[2048] | rn f[NB] | cn f[NL*NK] | cnt u32[NB] | cand u32[NB*16] | idx i32[NB]
  double* lacc = (double*)ws;
  float* rn = (float*)(ws + 16384);
  float* cn = (float*)(ws + 16384 + 262144);
  unsigned int* cnt = (unsigned int*)(ws + 16384 + 262144 + 16384);
  unsigned int* cand = (unsigned int*)(ws + 16384 + 262144 + 16384 + 262144);
  int* idx = (int*)(ws + 16384 + 262144 + 16384 + 262144 + 4194304);

  float* resb = out;                       // residual lives in out[0..NB*ND); final overwrites
  float* codes = out + (size_t)NB * ND;    // codes [NL, NB] as float

  hipMemsetAsync(lacc, 0, NL * 512 * sizeof(double), stream);
  cn_kernel<<<NL * NK, 256, 0, stream>>>(cbs, cn);
  rn_kernel<<<NB / 2, 256, 0, stream>>>(z_e, rn);

  for (int l = 0; l < NL; ++l) {
    const float* rin = (l == 0) ? z_e : resb;
    const float* cbl = cbs + (size_t)l * NK * ND;
    hipMemsetAsync(cnt, 0, (size_t)NB * 4, stream);
    argmin_mfma<<<(NB / 128) * 2, 512, 0, stream>>>(rin, cbl, rn, cn + l * NK, cnt, cand);
    recheck_kernel<<<NB / 64, 256, 0, stream>>>(rin, cbl, rn, cn + l * NK, cnt, cand, idx);
    update_kernel<<<NB / 2, 256, 0, stream>>>(
        rin, cbl, idx, resb, codes + (size_t)l * NB, rn, lacc + (size_t)l * 512);
  }

  loss_reduce<<<1, 256, 0, stream>>>(lacc, out);
  final_kernel<<<(NB * (size_t)ND) / 4 / 256, 256, 0, stream>>>(z_e, cbs, out);
}